// Round 21
// baseline (370.263 us; speedup 1.0000x reference)
//
#include <hip/hip_runtime.h>
#include <hip/hip_bf16.h>
#include <string.h>

#define B_  2
#define N_  100000
#define NE_ 800000
#define F_  2
#define D_  128
#define TD_ 11
#define CD_ 32
#define SD_ 10

#define NODE_BX   782                      // ceil(N/128)
#define NODE_NB   (NODE_BX * F_ * B_)      // 3128
#define EDGE_BX   6250                     // NE/128
#define EDGE_NB   (EDGE_BX * B_)           // 12500
#define GROUPS    3125                     // groups of 5 (1 node + 4 edge)
#define TOTAL_NB  (NODE_NB + EDGE_NB)      // 15628

// workspace byte offsets
#define WS_GB      0        // float[512]  gamma/beta
#define WS_FLAG    2048     // float       edges-are-int64 flag
#define WS_W1FRAG  2112     // bf16[3][8][64][8]  stage-1 A-frags (W1^T, bias as k=4)
#define WS_W2FRAG  26688    // bf16[3][2048][8]   stage-2 A-frags (w2, k-permuted)

typedef short s16x8 __attribute__((ext_vector_type(8)));
typedef float f32x4 __attribute__((ext_vector_type(4)));
typedef unsigned u32x4 __attribute__((ext_vector_type(4)));

static __device__ __forceinline__ unsigned short f2bf(float f) {
    unsigned u = __builtin_bit_cast(unsigned, f);
    u += 0x7FFFu + ((u >> 16) & 1u);   // RNE (prep kernel only)
    return (unsigned short)(u >> 16);
}
static __device__ __forceinline__ float silu_f(float x) {
    return x * __builtin_amdgcn_rcpf(1.0f + __expf(-x));
}
static __device__ __forceinline__ unsigned pack_bf16(float lo, float hi) {
    __hip_bfloat162 c = __float22bfloat162_rn(make_float2(lo, hi));
    unsigned r;
    memcpy(&r, &c, sizeof(r));
    return r;
}
// wave-local LDS fence: epilogue tile rows are wave-private (32-row slab), so
// no block barrier is needed — just retire this wave's outstanding LDS ops.
static __device__ __forceinline__ void wave_fence() {
    asm volatile("s_waitcnt lgkmcnt(0)" ::: "memory");
}

// ---------------------------------------------------------------------------
// Prep kernel (grid=6, 256 thr): FiLM (bx 0/1), w2 frag packs (bx 2/3/4,
// k-slots permuted to match stage-1 register layout), stage-1 W1^T frag packs
// + edge dtype probe (bx 5).   (unchanged, validated)
// ---------------------------------------------------------------------------
__global__ void prep_kernel(
    const float* __restrict__ time_i, const float* __restrict__ cond,
    const float* __restrict__ spat,
    const float* tw1, const float* tb1, const float* tw2, const float* tb2,
    const float* cw1, const float* cb1, const float* cw2, const float* cb2,
    const float* sw1, const float* sb1, const float* sw2, const float* sb2,
    const float* fuw1, const float* fub1, const float* fuw2, const float* fub2,
    const float* __restrict__ fw1, const float* __restrict__ fb1,
    const float* __restrict__ fw2,
    const float* __restrict__ ew1, const float* __restrict__ eb1,
    const float* __restrict__ ew2,
    const int* __restrict__ edges,
    char* __restrict__ ws)
{
    const int bx = blockIdx.x, t = threadIdx.x;

    if (bx < 2) {
        const int b = bx, d = t;
        __shared__ float h[3 * D_];
        __shared__ float hid[D_];

        const float* X [3] = { cond + b * CD_, time_i + b * TD_, spat + b * SD_ };
        const float* W1[3] = { cw1, tw1, sw1 };
        const float* B1[3] = { cb1, tb1, sb1 };
        const float* W2[3] = { cw2, tw2, sw2 };
        const float* B2[3] = { cb2, tb2, sb2 };
        const int    K [3] = { CD_, TD_, SD_ };

        for (int m = 0; m < 3; ++m) {
            float a = 0.f;
            if (d < D_) {
                a = B1[m][d];
                for (int k = 0; k < K[m]; ++k) a += X[m][k] * W1[m][k * D_ + d];
            }
            __syncthreads();
            if (d < D_) hid[d] = a / (1.0f + __expf(-a));   // exact silu (cold path)
            __syncthreads();
            if (d < D_) {
                float o = B2[m][d];
                for (int k = 0; k < D_; ++k) o += hid[k] * W2[m][k * D_ + d];
                h[m * D_ + d] = o;
            }
        }
        __syncthreads();
        float pre2 = 0.f;
        if (d < D_) {
            pre2 = fub1[d];
            for (int k = 0; k < 3 * D_; ++k) pre2 += h[k] * fuw1[k * D_ + d];
        }
        __syncthreads();
        if (d < D_) hid[d] = pre2 / (1.0f + __expf(-pre2));
        __syncthreads();
        if (d < D_) {
            float g = fub2[d], be = fub2[D_ + d];
            for (int k = 0; k < D_; ++k) {
                float hv = hid[k];
                g  += hv * fuw2[k * 2 * D_ + d];
                be += hv * fuw2[k * 2 * D_ + D_ + d];
            }
            float* gb = (float*)ws;
            gb[(b * 2 + 0) * D_ + d] = g;
            gb[(b * 2 + 1) * D_ + d] = be;
        }
    } else if (bx < 5) {
        // w2 A-frags with k-slot permutation matching stage-1 D layout:
        // slot (kb, kg, i) holds hidden = 32kb + 16(i>>2) + 4kg + 2((i>>1)&1) + (i&1)
        const int which = bx - 2;
        const float* src = (which < 2) ? (fw2 + which * D_ * D_) : ew2;
        unsigned short* dst = (unsigned short*)(ws + WS_W2FRAG) + (long)which * 2048 * 8;
        for (int e = t; e < 2048; e += 256) {
            const int lanee = e & 63, kb = (e >> 6) & 3, nt = e >> 8;
            const int out = nt * 16 + (lanee & 15);
            const int kgA = lanee >> 4;
            s16x8 v;
            #pragma unroll
            for (int i = 0; i < 8; ++i) {
                const int hid = kb * 32 + ((i >> 2) << 4) + kgA * 4
                              + (((i >> 1) & 1) << 1) + (i & 1);
                v[i] = (short)f2bf(src[hid * D_ + out]);
            }
            *(s16x8*)(dst + e * 8) = v;
        }
    } else {
        if (t == 0) {   // int64 edges => odd int32 words of first 64 all 0
            int nz = 0;
            for (int j = 0; j < 64; ++j) nz |= edges[2 * j + 1];
            ((float*)(ws + WS_FLAG))[0] = (nz == 0) ? 1.0f : 0.0f;
        }
        // stage-1 A-frags: A[m=hid][k] = W1ext[k][hid], bias as k=4 row.
        // layout [which][h8][lane][8]; lane: m = h8*16 + (lane&15), k = (lane>>4)*8+i
        unsigned short* w1f = (unsigned short*)(ws + WS_W1FRAG);
        for (int e = t; e < 1536; e += 256) {
            const int which = e >> 9;
            const int h8    = (e >> 6) & 7;
            const int lane  = e & 63;
            const int m  = h8 * 16 + (lane & 15);
            const int kg = lane >> 4;
            s16x8 v;
            #pragma unroll
            for (int i = 0; i < 8; ++i) {
                const int k = kg * 8 + i;
                float val = 0.f;
                if (kg == 0) {
                    if (which < 2) {
                        if (k < 4)      val = fw1[(which * 4 + k) * D_ + m];
                        else if (k == 4) val = fb1[which * D_ + m];
                    } else {
                        if (k < 3)      val = ew1[k * D_ + m] - ew1[(k + 3) * D_ + m];
                        else if (k == 3) val = ew1[6 * D_ + m];
                        else if (k == 4) val = eb1[m];
                    }
                }
                v[i] = (short)f2bf(val);
            }
            *(s16x8*)(w1f + e * 8) = v;
        }
    }
}

// ---------------------------------------------------------------------------
// Fused kernel: 256 thr, 128 rows/block, node/edge 1:4.
//  - ZERO block barriers: w2 frags read direct from ws (L1/L2-hot, 48KB shared;
//    NT output stores bypass L2 so it stays hot); epilogue tile rows wave-private.
//  - stage-1 both rows -> registers; stage-2 column-split (acc[2][4] = 32 VGPR)
//  - LDS = [128][68] f32 tile (34.8KB; each p-half covers 64 cols — r20's
//    [128][34] slab was a 64-col-into-34-stride overflow, the correctness bug).
// ---------------------------------------------------------------------------
__global__ __launch_bounds__(256, 4) void fused_kernel(
    const float* __restrict__ pos, const float* __restrict__ state,
    const int* __restrict__ edges,
    const float* __restrict__ fb2, const float* __restrict__ eb2,
    const char* __restrict__ ws,
    float* __restrict__ V, float* __restrict__ E)
{
    __shared__ __align__(16) float outF[128 * 68];   // 34816B, wave-private rows

    const int bx = blockIdx.x, t = threadIdx.x;
    const int lane = t & 63, wv = t >> 6;
    const int kg = lane >> 4, lr = lane & 15;

    const float* gbAll = (const float*)ws;
    const char*  w1fB  = ws + WS_W1FRAG;

    bool isNode; int sub;
    if (bx >= 5 * GROUPS) { isNode = true; sub = GROUPS + (bx - 5 * GROUPS); }
    else {
        int g = bx / 5, s = bx - 5 * g;
        if (s == 0) { isNode = true;  sub = g; }
        else        { isNode = false; sub = g * 4 + (s - 1); }
    }

    // ---- role decode + input gather ----
    float xa[4], xb[4];
    int n0 = 0, f = 0, b, e0blk = 0;
    if (isNode) {
        n0 = (sub % NODE_BX) * 128;
        f  = (sub / NODE_BX) & 1;
        b  = sub / (NODE_BX * F_);
        int na = n0 + wv * 32 + lr;      if (na >= N_) na = N_ - 1;
        int nb = n0 + wv * 32 + lr + 16; if (nb >= N_) nb = N_ - 1;
        long pa = ((long)b * N_ + na) * 3, pb = ((long)b * N_ + nb) * 3;
        xa[0] = pos[pa]; xa[1] = pos[pa + 1]; xa[2] = pos[pa + 2];
        xb[0] = pos[pb]; xb[1] = pos[pb + 1]; xb[2] = pos[pb + 2];
        xa[3] = state[((long)b * N_ + na) * F_ + f];
        xb[3] = state[((long)b * N_ + nb) * F_ + f];
    } else {
        e0blk = (sub % EDGE_BX) * 128;
        b     = sub / EDGE_BX;
        const bool x64 = ((const float*)(ws + WS_FLAG))[0] > 0.5f;
        const long ea = (long)b * NE_ + e0blk + wv * 32 + lr;
        const long eb = ea + 16;
        int sa, ra, sb, rb;
        if (x64) {
            sa = edges[ea * 4]; ra = edges[ea * 4 + 2];
            sb = edges[eb * 4]; rb = edges[eb * 4 + 2];
        } else {
            int2 va = *(const int2*)(edges + ea * 2); sa = va.x; ra = va.y;
            int2 vb = *(const int2*)(edges + eb * 2); sb = vb.x; rb = vb.y;
        }
        const float* pp = pos + (long)b * N_ * 3;
        {
            long so = (long)sa * 3, ro = (long)ra * 3;
            xa[0] = pp[ro]     - pp[so];
            xa[1] = pp[ro + 1] - pp[so + 1];
            xa[2] = pp[ro + 2] - pp[so + 2];
            xa[3] = sqrtf(xa[0]*xa[0] + xa[1]*xa[1] + xa[2]*xa[2] + 1e-8f);
        }
        {
            long so = (long)sb * 3, ro = (long)rb * 3;
            xb[0] = pp[ro]     - pp[so];
            xb[1] = pp[ro + 1] - pp[so + 1];
            xb[2] = pp[ro + 2] - pp[so + 2];
            xb[3] = sqrtf(xb[0]*xb[0] + xb[1]*xb[1] + xb[2]*xb[2] + 1e-8f);
        }
    }

    const int which = isNode ? f : 2;
    const char* w1fr = w1fB + which * 8192;                       // [8][64][8] bf16
    const s16x8* w2p = ((const s16x8*)(ws + WS_W2FRAG))
                     + (long)which * 2048 + lane;                 // frag (nt*4+kb)*64
    const f32x4 zero4 = (f32x4){0.f, 0.f, 0.f, 0.f};

    // ---- stage-1 for BOTH rows: hidden -> silu -> bf16 dwords in registers ----
    uint2 d0[8], d1[8];
    {
        s16x8 bop0, bop1;
        {
            u32x4 bf;
            bf[0] = pack_bf16(xa[0], xa[1]); bf[1] = pack_bf16(xa[2], xa[3]);
            bf[2] = 0x00003F80u;             bf[3] = 0u;
            memcpy(&bop0, &bf, sizeof(bop0));
            bf[0] = pack_bf16(xb[0], xb[1]); bf[1] = pack_bf16(xb[2], xb[3]);
            memcpy(&bop1, &bf, sizeof(bop1));
        }
        #pragma unroll
        for (int h8 = 0; h8 < 8; ++h8) {
            s16x8 af = *(const s16x8*)(w1fr + h8 * 1024 + lane * 16);
            f32x4 h4 = __builtin_amdgcn_mfma_f32_16x16x32_bf16(af, bop0, zero4, 0, 0, 0);
            f32x4 g4 = __builtin_amdgcn_mfma_f32_16x16x32_bf16(af, bop1, zero4, 0, 0, 0);
            d0[h8].x = pack_bf16(silu_f(h4[0]), silu_f(h4[1]));
            d0[h8].y = pack_bf16(silu_f(h4[2]), silu_f(h4[3]));
            d1[h8].x = pack_bf16(silu_f(g4[0]), silu_f(g4[1]));
            d1[h8].y = pack_bf16(silu_f(g4[2]), silu_f(g4[3]));
        }
    }

    // ---- per-role epilogue constants ----
    const float* bias  = isNode ? (fb2 + f * D_) : eb2;
    const float* gamma = gbAll + b * 2 * D_;
    const float* beta  = gamma + D_;
    float* base = isNode ? (V + (((long)b * N_ + n0) * F_ + f) * D_)
                         : (E + ((long)b * NE_ + e0blk) * D_);
    const long stride   = isNode ? (long)F_ * D_ : (long)D_;   // floats
    const int rowsValid = isNode ? (N_ - n0) : 128;

    // ---- column halves: stage-2 (w2 direct from global) + epilogue ----
    #pragma unroll
    for (int p = 0; p < 2; ++p) {
        f32x4 acc[2][4];
        #pragma unroll
        for (int rt = 0; rt < 2; ++rt)
            #pragma unroll
            for (int ntl = 0; ntl < 4; ++ntl) acc[rt][ntl] = zero4;

        #pragma unroll
        for (int kb = 0; kb < 4; ++kb) {
            s16x8 u0, u1;
            {
                u32x4 uw;
                uw[0] = d0[2 * kb].x;     uw[1] = d0[2 * kb].y;
                uw[2] = d0[2 * kb + 1].x; uw[3] = d0[2 * kb + 1].y;
                memcpy(&u0, &uw, sizeof(u0));
                uw[0] = d1[2 * kb].x;     uw[1] = d1[2 * kb].y;
                uw[2] = d1[2 * kb + 1].x; uw[3] = d1[2 * kb + 1].y;
                memcpy(&u1, &uw, sizeof(u1));
            }
            #pragma unroll
            for (int ntl = 0; ntl < 4; ++ntl) {
                const int nt = p * 4 + ntl;
                s16x8 afr = w2p[(nt * 4 + kb) * 64];
                acc[0][ntl] = __builtin_amdgcn_mfma_f32_16x16x32_bf16(afr, u0, acc[0][ntl], 0, 0, 0);
                acc[1][ntl] = __builtin_amdgcn_mfma_f32_16x16x32_bf16(afr, u1, acc[1][ntl], 0, 0, 0);
            }
        }

        // epilogue half: bias(+FiLM) -> wave-private LDS rows -> full-line NT stores
        #pragma unroll
        for (int ntl = 0; ntl < 4; ++ntl) {
            const int gc = (p * 4 + ntl) * 16 + kg * 4;   // global col
            const int lc = ntl * 16 + kg * 4;             // local slab col (0..60)
            const f32x4 bs = *(const f32x4*)(bias + gc);
            f32x4 g, be;
            if (isNode) { g = *(const f32x4*)(gamma + gc); be = *(const f32x4*)(beta + gc); }
            #pragma unroll
            for (int mt = 0; mt < 2; ++mt) {
                const int m = wv * 32 + mt * 16 + lr;
                f32x4 v;
                #pragma unroll
                for (int r = 0; r < 4; ++r)
                    v[r] = isNode ? (acc[mt][ntl][r] + bs[r]) * g[r] + be[r]
                                  : acc[mt][ntl][r] + bs[r];
                *(f32x4*)(outF + m * 68 + lc) = v;
            }
        }
        wave_fence();   // slab writes retired (rows wave-private -> no s_barrier)
        #pragma unroll
        for (int j = 0; j < 8; ++j) {
            const int r = wv * 32 + j * 4 + (lane >> 4);
            const int c = (lane & 15) * 4;
            f32x4 v = *(const f32x4*)(outF + r * 68 + c);
            if (r < rowsValid)
                __builtin_nontemporal_store(v, (f32x4*)(base + (long)r * stride + p * 64 + c));
        }
        wave_fence();   // slab reads retired before p=1 overwrites
    }
}

// ---------------------------------------------------------------------------
extern "C" void kernel_launch(void* const* d_in, const int* in_sizes, int n_in,
                              void* d_out, int out_size, void* d_ws, size_t ws_size,
                              hipStream_t stream)
{
    (void)in_sizes; (void)n_in; (void)out_size; (void)ws_size;

    const float* node_pos  = (const float*)d_in[0];
    const float* state_in  = (const float*)d_in[1];
    const float* time_i    = (const float*)d_in[2];
    const float* conditions= (const float*)d_in[3];
    const float* spatial   = (const float*)d_in[4];
    const int*   edges     = (const int*)d_in[5];
    const float* fields_w1 = (const float*)d_in[6];
    const float* fields_b1 = (const float*)d_in[7];
    const float* fields_w2 = (const float*)d_in[8];
    const float* fields_b2 = (const float*)d_in[9];
    const float* tw1 = (const float*)d_in[10];
    const float* tb1 = (const float*)d_in[11];
    const float* tw2 = (const float*)d_in[12];
    const float* tb2 = (const float*)d_in[13];
    const float* cw1 = (const float*)d_in[14];
    const float* cb1 = (const float*)d_in[15];
    const float* cw2 = (const float*)d_in[16];
    const float* cb2 = (const float*)d_in[17];
    const float* sw1 = (const float*)d_in[18];
    const float* sb1 = (const float*)d_in[19];
    const float* sw2 = (const float*)d_in[20];
    const float* sb2 = (const float*)d_in[21];
    const float* fu_w1 = (const float*)d_in[22];
    const float* fu_b1 = (const float*)d_in[23];
    const float* fu_w2 = (const float*)d_in[24];
    const float* fu_b2 = (const float*)d_in[25];
    const float* fe_w1 = (const float*)d_in[26];
    const float* fe_b1 = (const float*)d_in[27];
    const float* fe_w2 = (const float*)d_in[28];
    const float* fe_b2 = (const float*)d_in[29];

    char*  ws = (char*)d_ws;
    float* V  = (float*)d_out;                // [B][N][F][D] f32
    float* E  = V + (long)B_ * N_ * F_ * D_;  // [B][NE][D] f32

    prep_kernel<<<dim3(6), dim3(256), 0, stream>>>(
        time_i, conditions, spatial,
        tw1, tb1, tw2, tb2, cw1, cb1, cw2, cb2, sw1, sb1, sw2, sb2,
        fu_w1, fu_b1, fu_w2, fu_b2,
        fields_w1, fields_b1, fields_w2,
        fe_w1, fe_b1, fe_w2,
        edges, ws);

    fused_kernel<<<dim3(TOTAL_NB), dim3(256), 0, stream>>>(
        node_pos, state_in, edges, fields_b2, fe_b2, ws, V, E);
}

// Round 22
// 229.890 us; speedup vs baseline: 1.6106x; 1.6106x over previous
//
#include <hip/hip_runtime.h>
#include <hip/hip_bf16.h>
#include <string.h>

#define B_  2
#define N_  100000
#define NE_ 800000
#define F_  2
#define D_  128
#define TD_ 11
#define CD_ 32
#define SD_ 10

#define NODE_BX   782                      // ceil(N/128)
#define NODE_NB   (NODE_BX * F_ * B_)      // 3128
#define EDGE_BX   6250                     // NE/128
#define EDGE_NB   (EDGE_BX * B_)           // 12500
#define GROUPS    3125                     // groups of 5 (1 node + 4 edge)
#define TOTAL_NB  (NODE_NB + EDGE_NB)      // 15628

// workspace byte offsets
#define WS_GB      0        // float[512]  gamma/beta
#define WS_FLAG    2048     // float       edges-are-int64 flag
#define WS_W1FRAG  2112     // bf16[3][8][64][8]  stage-1 A-frags (W1^T, bias as k=4)
#define WS_W2FRAG  26688    // bf16[3][2048][8]   stage-2 A-frags (w2, k-permuted)

typedef short s16x8 __attribute__((ext_vector_type(8)));
typedef float f32x4 __attribute__((ext_vector_type(4)));
typedef unsigned u32x4 __attribute__((ext_vector_type(4)));

static __device__ __forceinline__ unsigned short f2bf(float f) {
    unsigned u = __builtin_bit_cast(unsigned, f);
    u += 0x7FFFu + ((u >> 16) & 1u);   // RNE (prep kernel only)
    return (unsigned short)(u >> 16);
}
static __device__ __forceinline__ float silu_f(float x) {
    return x * __builtin_amdgcn_rcpf(1.0f + __expf(-x));
}
static __device__ __forceinline__ unsigned pack_bf16(float lo, float hi) {
    __hip_bfloat162 c = __float22bfloat162_rn(make_float2(lo, hi));
    unsigned r;
    memcpy(&r, &c, sizeof(r));
    return r;
}
// barrier with LDS-only ordering (no vmcnt drain)
static __device__ __forceinline__ void lds_barrier() {
    asm volatile("s_waitcnt lgkmcnt(0)" ::: "memory");
    __builtin_amdgcn_s_barrier();
}

// ---------------------------------------------------------------------------
// Prep kernel (grid=6, 256 thr): FiLM (bx 0/1), w2 frag packs (bx 2/3/4,
// k-slots permuted to match stage-1 register layout), stage-1 W1^T frag packs
// + edge dtype probe (bx 5).
// ---------------------------------------------------------------------------
__global__ void prep_kernel(
    const float* __restrict__ time_i, const float* __restrict__ cond,
    const float* __restrict__ spat,
    const float* tw1, const float* tb1, const float* tw2, const float* tb2,
    const float* cw1, const float* cb1, const float* cw2, const float* cb2,
    const float* sw1, const float* sb1, const float* sw2, const float* sb2,
    const float* fuw1, const float* fub1, const float* fuw2, const float* fub2,
    const float* __restrict__ fw1, const float* __restrict__ fb1,
    const float* __restrict__ fw2,
    const float* __restrict__ ew1, const float* __restrict__ eb1,
    const float* __restrict__ ew2,
    const int* __restrict__ edges,
    char* __restrict__ ws)
{
    const int bx = blockIdx.x, t = threadIdx.x;

    if (bx < 2) {
        const int b = bx, d = t;
        __shared__ float h[3 * D_];
        __shared__ float hid[D_];

        const float* X [3] = { cond + b * CD_, time_i + b * TD_, spat + b * SD_ };
        const float* W1[3] = { cw1, tw1, sw1 };
        const float* B1[3] = { cb1, tb1, sb1 };
        const float* W2[3] = { cw2, tw2, sw2 };
        const float* B2[3] = { cb2, tb2, sb2 };
        const int    K [3] = { CD_, TD_, SD_ };

        for (int m = 0; m < 3; ++m) {
            float a = 0.f;
            if (d < D_) {
                a = B1[m][d];
                for (int k = 0; k < K[m]; ++k) a += X[m][k] * W1[m][k * D_ + d];
            }
            __syncthreads();
            if (d < D_) hid[d] = a / (1.0f + __expf(-a));   // exact silu (cold path)
            __syncthreads();
            if (d < D_) {
                float o = B2[m][d];
                for (int k = 0; k < D_; ++k) o += hid[k] * W2[m][k * D_ + d];
                h[m * D_ + d] = o;
            }
        }
        __syncthreads();
        float pre2 = 0.f;
        if (d < D_) {
            pre2 = fub1[d];
            for (int k = 0; k < 3 * D_; ++k) pre2 += h[k] * fuw1[k * D_ + d];
        }
        __syncthreads();
        if (d < D_) hid[d] = pre2 / (1.0f + __expf(-pre2));
        __syncthreads();
        if (d < D_) {
            float g = fub2[d], be = fub2[D_ + d];
            for (int k = 0; k < D_; ++k) {
                float hv = hid[k];
                g  += hv * fuw2[k * 2 * D_ + d];
                be += hv * fuw2[k * 2 * D_ + D_ + d];
            }
            float* gb = (float*)ws;
            gb[(b * 2 + 0) * D_ + d] = g;
            gb[(b * 2 + 1) * D_ + d] = be;
        }
    } else if (bx < 5) {
        // w2 A-frags with k-slot permutation matching stage-1 D layout:
        // slot (kb, kg, i) holds hidden = 32kb + 16(i>>2) + 4kg + 2((i>>1)&1) + (i&1)
        const int which = bx - 2;
        const float* src = (which < 2) ? (fw2 + which * D_ * D_) : ew2;
        unsigned short* dst = (unsigned short*)(ws + WS_W2FRAG) + (long)which * 2048 * 8;
        for (int e = t; e < 2048; e += 256) {
            const int lanee = e & 63, kb = (e >> 6) & 3, nt = e >> 8;
            const int out = nt * 16 + (lanee & 15);
            const int kgA = lanee >> 4;
            s16x8 v;
            #pragma unroll
            for (int i = 0; i < 8; ++i) {
                const int hid = kb * 32 + ((i >> 2) << 4) + kgA * 4
                              + (((i >> 1) & 1) << 1) + (i & 1);
                v[i] = (short)f2bf(src[hid * D_ + out]);
            }
            *(s16x8*)(dst + e * 8) = v;
        }
    } else {
        if (t == 0) {   // int64 edges => odd int32 words of first 64 all 0
            int nz = 0;
            for (int j = 0; j < 64; ++j) nz |= edges[2 * j + 1];
            ((float*)(ws + WS_FLAG))[0] = (nz == 0) ? 1.0f : 0.0f;
        }
        // stage-1 A-frags: A[m=hid][k] = W1ext[k][hid], bias as k=4 row.
        // layout [which][h8][lane][8]; lane: m = h8*16 + (lane&15), k = (lane>>4)*8+i
        unsigned short* w1f = (unsigned short*)(ws + WS_W1FRAG);
        for (int e = t; e < 1536; e += 256) {
            const int which = e >> 9;
            const int h8    = (e >> 6) & 7;
            const int lane  = e & 63;
            const int m  = h8 * 16 + (lane & 15);
            const int kg = lane >> 4;
            s16x8 v;
            #pragma unroll
            for (int i = 0; i < 8; ++i) {
                const int k = kg * 8 + i;
                float val = 0.f;
                if (kg == 0) {
                    if (which < 2) {
                        if (k < 4)      val = fw1[(which * 4 + k) * D_ + m];
                        else if (k == 4) val = fb1[which * D_ + m];
                    } else {
                        if (k < 3)      val = ew1[k * D_ + m] - ew1[(k + 3) * D_ + m];
                        else if (k == 3) val = ew1[6 * D_ + m];
                        else if (k == 4) val = eb1[m];
                    }
                }
                v[i] = (short)f2bf(val);
            }
            *(s16x8*)(w1f + e * 8) = v;
        }
    }
}

// ---------------------------------------------------------------------------
// Fused kernel (r18 config — best measured, 230.7us): 256 thr, 128 rows/block,
// node/edge 1:4.  Dual-MFMA, all-register handoff (k-permutation absorbed into
// w2 pack).  w2 staged ws->LDS once per block.  __launch_bounds__(256,3).
// ---------------------------------------------------------------------------
__global__ __launch_bounds__(256, 3) void fused_kernel(
    const float* __restrict__ pos, const float* __restrict__ state,
    const int* __restrict__ edges,
    const float* __restrict__ fb2, const float* __restrict__ eb2,
    const char* __restrict__ ws,
    float* __restrict__ V, float* __restrict__ E)
{
    __shared__ __align__(16) char smem[34816];
    unsigned short* w2lds = (unsigned short*)smem;   // 32KB (dead after stage-2)
    float* outF = (float*)smem;                      // [128][68] f32 (aliases)

    const int bx = blockIdx.x, t = threadIdx.x;
    const int lane = t & 63, wv = t >> 6;
    const int kg = lane >> 4, lr = lane & 15;

    const float* gbAll = (const float*)ws;
    const char*  w1fB  = ws + WS_W1FRAG;
    const unsigned short* w2all = (const unsigned short*)(ws + WS_W2FRAG);

    bool isNode; int sub;
    if (bx >= 5 * GROUPS) { isNode = true; sub = GROUPS + (bx - 5 * GROUPS); }
    else {
        int g = bx / 5, s = bx - 5 * g;
        if (s == 0) { isNode = true;  sub = g; }
        else        { isNode = false; sub = g * 4 + (s - 1); }
    }

    // ---- role decode + input gather ----
    float xa[4], xb[4];
    int n0 = 0, f = 0, b, e0blk = 0;
    if (isNode) {
        n0 = (sub % NODE_BX) * 128;
        f  = (sub / NODE_BX) & 1;
        b  = sub / (NODE_BX * F_);
        int na = n0 + wv * 32 + lr;      if (na >= N_) na = N_ - 1;
        int nb = n0 + wv * 32 + lr + 16; if (nb >= N_) nb = N_ - 1;
        long pa = ((long)b * N_ + na) * 3, pb = ((long)b * N_ + nb) * 3;
        xa[0] = pos[pa]; xa[1] = pos[pa + 1]; xa[2] = pos[pa + 2];
        xb[0] = pos[pb]; xb[1] = pos[pb + 1]; xb[2] = pos[pb + 2];
        xa[3] = state[((long)b * N_ + na) * F_ + f];
        xb[3] = state[((long)b * N_ + nb) * F_ + f];
    } else {
        e0blk = (sub % EDGE_BX) * 128;
        b     = sub / EDGE_BX;
        const bool x64 = ((const float*)(ws + WS_FLAG))[0] > 0.5f;
        const long ea = (long)b * NE_ + e0blk + wv * 32 + lr;
        const long eb = ea + 16;
        int sa, ra, sb, rb;
        if (x64) {
            sa = edges[ea * 4]; ra = edges[ea * 4 + 2];
            sb = edges[eb * 4]; rb = edges[eb * 4 + 2];
        } else {
            int2 va = *(const int2*)(edges + ea * 2); sa = va.x; ra = va.y;
            int2 vb = *(const int2*)(edges + eb * 2); sb = vb.x; rb = vb.y;
        }
        const float* pp = pos + (long)b * N_ * 3;
        {
            long so = (long)sa * 3, ro = (long)ra * 3;
            xa[0] = pp[ro]     - pp[so];
            xa[1] = pp[ro + 1] - pp[so + 1];
            xa[2] = pp[ro + 2] - pp[so + 2];
            xa[3] = sqrtf(xa[0]*xa[0] + xa[1]*xa[1] + xa[2]*xa[2] + 1e-8f);
        }
        {
            long so = (long)sb * 3, ro = (long)rb * 3;
            xb[0] = pp[ro]     - pp[so];
            xb[1] = pp[ro + 1] - pp[so + 1];
            xb[2] = pp[ro + 2] - pp[so + 2];
            xb[3] = sqrtf(xb[0]*xb[0] + xb[1]*xb[1] + xb[2]*xb[2] + 1e-8f);
        }
    }

    const int which = isNode ? f : 2;

    // ---- stage w2 frags (32KB) into LDS ----
    {
        const char* src = (const char*)(w2all + (long)which * 2048 * 8);
        #pragma unroll
        for (int j = 0; j < 8; ++j) {
            f32x4 v = *(const f32x4*)(src + (j * 256 + t) * 16);
            *(f32x4*)((char*)w2lds + (j * 256 + t) * 16) = v;
        }
    }
    __syncthreads();   // w2lds ready for stage-2

    const char* w1fr = w1fB + which * 8192;   // [8][64][8] bf16
    const f32x4 zero4 = (f32x4){0.f, 0.f, 0.f, 0.f};

    // ---- stage-1 for BOTH rows: hidden -> silu -> bf16 dwords in registers ----
    uint2 d0[8], d1[8];
    {
        s16x8 bop0, bop1;
        {
            u32x4 bf;
            bf[0] = pack_bf16(xa[0], xa[1]); bf[1] = pack_bf16(xa[2], xa[3]);
            bf[2] = 0x00003F80u;             bf[3] = 0u;
            memcpy(&bop0, &bf, sizeof(bop0));
            bf[0] = pack_bf16(xb[0], xb[1]); bf[1] = pack_bf16(xb[2], xb[3]);
            memcpy(&bop1, &bf, sizeof(bop1));
        }
        #pragma unroll
        for (int h8 = 0; h8 < 8; ++h8) {
            s16x8 af = *(const s16x8*)(w1fr + h8 * 1024 + lane * 16);
            f32x4 h4 = __builtin_amdgcn_mfma_f32_16x16x32_bf16(af, bop0, zero4, 0, 0, 0);
            f32x4 g4 = __builtin_amdgcn_mfma_f32_16x16x32_bf16(af, bop1, zero4, 0, 0, 0);
            d0[h8].x = pack_bf16(silu_f(h4[0]), silu_f(h4[1]));
            d0[h8].y = pack_bf16(silu_f(h4[2]), silu_f(h4[3]));
            d1[h8].x = pack_bf16(silu_f(g4[0]), silu_f(g4[1]));
            d1[h8].y = pack_bf16(silu_f(g4[2]), silu_f(g4[3]));
        }
    }

    // ---- stage-2: B-frag = registers from stage-1 (k-permutation in w2 pack) ----
    f32x4 acc[2][8];
    #pragma unroll
    for (int rt = 0; rt < 2; ++rt)
        #pragma unroll
        for (int nt = 0; nt < 8; ++nt) acc[rt][nt] = (f32x4){0.f, 0.f, 0.f, 0.f};

    #pragma unroll
    for (int kb = 0; kb < 4; ++kb) {
        s16x8 u0, u1;
        {
            u32x4 uw;
            uw[0] = d0[2 * kb].x;     uw[1] = d0[2 * kb].y;
            uw[2] = d0[2 * kb + 1].x; uw[3] = d0[2 * kb + 1].y;
            memcpy(&u0, &uw, sizeof(u0));
            uw[0] = d1[2 * kb].x;     uw[1] = d1[2 * kb].y;
            uw[2] = d1[2 * kb + 1].x; uw[3] = d1[2 * kb + 1].y;
            memcpy(&u1, &uw, sizeof(u1));
        }
        #pragma unroll
        for (int nt = 0; nt < 8; ++nt) {
            s16x8 afr = *(const s16x8*)(w2lds + ((nt * 4 + kb) * 64 + lane) * 8);
            acc[0][nt] = __builtin_amdgcn_mfma_f32_16x16x32_bf16(afr, u0, acc[0][nt], 0, 0, 0);
            acc[1][nt] = __builtin_amdgcn_mfma_f32_16x16x32_bf16(afr, u1, acc[1][nt], 0, 0, 0);
        }
    }

    // ---- epilogue: bias(+FiLM) -> LDS tile (stride 68) -> full-line NT stores ----
    const float* bias  = isNode ? (fb2 + f * D_) : eb2;
    const float* gamma = gbAll + b * 2 * D_;
    const float* beta  = gamma + D_;
    float* base = isNode ? (V + (((long)b * N_ + n0) * F_ + f) * D_)
                         : (E + ((long)b * NE_ + e0blk) * D_);
    const long stride   = isNode ? (long)F_ * D_ : (long)D_;   // floats
    const int rowsValid = isNode ? (N_ - n0) : 128;

    lds_barrier();   // all stage-2 w2lds reads done -> outF may alias

    #pragma unroll
    for (int p = 0; p < 2; ++p) {
        #pragma unroll
        for (int ntl = 0; ntl < 4; ++ntl) {
            const int nt = p * 4 + ntl;
            const int d0c = nt * 16 + kg * 4;
            const f32x4 bs = *(const f32x4*)(bias + d0c);
            f32x4 g, be;
            if (isNode) { g = *(const f32x4*)(gamma + d0c); be = *(const f32x4*)(beta + d0c); }
            #pragma unroll
            for (int mt = 0; mt < 2; ++mt) {
                const int m = wv * 32 + mt * 16 + lr;
                f32x4 v;
                #pragma unroll
                for (int r = 0; r < 4; ++r)
                    v[r] = isNode ? (acc[mt][nt][r] + bs[r]) * g[r] + be[r]
                                  : acc[mt][nt][r] + bs[r];
                *(f32x4*)(outF + m * 68 + ntl * 16 + kg * 4) = v;
            }
        }
        lds_barrier();
        #pragma unroll
        for (int j = 0; j < 8; ++j) {
            const int r = wv * 32 + j * 4 + (lane >> 4);
            const int c = (lane & 15) * 4;
            f32x4 v = *(const f32x4*)(outF + r * 68 + c);
            if (r < rowsValid)
                __builtin_nontemporal_store(v, (f32x4*)(base + (long)r * stride + p * 64 + c));
        }
        if (p == 0) lds_barrier();
    }
}

// ---------------------------------------------------------------------------
extern "C" void kernel_launch(void* const* d_in, const int* in_sizes, int n_in,
                              void* d_out, int out_size, void* d_ws, size_t ws_size,
                              hipStream_t stream)
{
    (void)in_sizes; (void)n_in; (void)out_size; (void)ws_size;

    const float* node_pos  = (const float*)d_in[0];
    const float* state_in  = (const float*)d_in[1];
    const float* time_i    = (const float*)d_in[2];
    const float* conditions= (const float*)d_in[3];
    const float* spatial   = (const float*)d_in[4];
    const int*   edges     = (const int*)d_in[5];
    const float* fields_w1 = (const float*)d_in[6];
    const float* fields_b1 = (const float*)d_in[7];
    const float* fields_w2 = (const float*)d_in[8];
    const float* fields_b2 = (const float*)d_in[9];
    const float* tw1 = (const float*)d_in[10];
    const float* tb1 = (const float*)d_in[11];
    const float* tw2 = (const float*)d_in[12];
    const float* tb2 = (const float*)d_in[13];
    const float* cw1 = (const float*)d_in[14];
    const float* cb1 = (const float*)d_in[15];
    const float* cw2 = (const float*)d_in[16];
    const float* cb2 = (const float*)d_in[17];
    const float* sw1 = (const float*)d_in[18];
    const float* sb1 = (const float*)d_in[19];
    const float* sw2 = (const float*)d_in[20];
    const float* sb2 = (const float*)d_in[21];
    const float* fu_w1 = (const float*)d_in[22];
    const float* fu_b1 = (const float*)d_in[23];
    const float* fu_w2 = (const float*)d_in[24];
    const float* fu_b2 = (const float*)d_in[25];
    const float* fe_w1 = (const float*)d_in[26];
    const float* fe_b1 = (const float*)d_in[27];
    const float* fe_w2 = (const float*)d_in[28];
    const float* fe_b2 = (const float*)d_in[29];

    char*  ws = (char*)d_ws;
    float* V  = (float*)d_out;                // [B][N][F][D] f32
    float* E  = V + (long)B_ * N_ * F_ * D_;  // [B][NE][D] f32

    prep_kernel<<<dim3(6), dim3(256), 0, stream>>>(
        time_i, conditions, spatial,
        tw1, tb1, tw2, tb2, cw1, cb1, cw2, cb2, sw1, sb1, sw2, sb2,
        fu_w1, fu_b1, fu_w2, fu_b2,
        fields_w1, fields_b1, fields_w2,
        fe_w1, fe_b1, fe_w2,
        edges, ws);

    fused_kernel<<<dim3(TOTAL_NB), dim3(256), 0, stream>>>(
        node_pos, state_in, edges, fields_b2, fe_b2, ws, V, E);
}